// Round 9
// baseline (158.078 us; speedup 1.0000x reference)
//
#include <hip/hip_runtime.h>
#include <hip/hip_bf16.h>

#define RS   100            // row stride (floats) of a 97x97 plane (padded for float4 alignment)
#define PLS  9700           // plane stride = 97 rows * RS
#define NP   9409           // 97*97 valid elements per plane
#define ASTR 34             // maxplus A-panel LDS stride: bank=(2k+r)%32 -> 2-way (free); 8B-aligned
#define BSTR 68             // maxplus B-panel LDS stride: staging banks consecutive; 16B-aligned

// ws layout (float offsets) — weights read directly from d_in (fp32)
#define OFF_R   0                          // 4*32 planes (pooled relations, padded/shifted)
#define OFF_A   (OFF_R  + 4*32*PLS)        // 4*16 planes (ft projection)
#define OFF_Bm  (OFF_A  + 4*16*PLS)        // 4*16 planes (rt projection)
#define OFF_F1  (OFF_Bm + 4*16*PLS)        // 4*16 planes (dp step-0 output)
#define OFF_F2  (OFF_F1 + 4*16*PLS)        // 4*16 planes (dp step-1 output)
// total = 384 planes * 9700 * 4 B = 14.9 MB of ws

__device__ __forceinline__ float sigm(float x) { return 1.0f / (1.0f + __expf(-x)); }

// ---------------- interval pooling (max & min) + pad -> R planes ----------------
__global__ __launch_bounds__(256) void pool_kernel(const float* __restrict__ a, float* __restrict__ R) {
    __shared__ float s[96][97];   // +1 pad: scans hit distinct banks both directions
    const int tid = threadIdx.x;
    const int b  = blockIdx.x >> 5;
    const int ch = blockIdx.x & 31;
    const int d  = ch & 15;
    const bool isMin = (ch >= 16);

    for (int idx = tid; idx < 96 * 96; idx += 256) {
        int i = idx / 96, j = idx - i * 96;
        float v = a[((size_t)(b * 96 + i) * 96 + j) * 16 + d];
        if (isMin) v = -v;
        s[i][j] = (j >= i) ? v : -1e30f;
    }
    __syncthreads();
    if (tid < 96) {              // reverse cummax over i (thread = column j)
        int j = tid; float run = -1e30f;
#pragma unroll 4
        for (int i = 95; i >= 0; --i) { run = fmaxf(run, s[i][j]); s[i][j] = run; }
    }
    __syncthreads();
    if (tid < 96) {              // forward cummax over j (thread = row i)
        int i = tid; float run = -1e30f;
#pragma unroll 4
        for (int j = 0; j < 96; ++j) { run = fmaxf(run, s[i][j]); s[i][j] = run; }
    }
    __syncthreads();
    float* Rp = R + (size_t)blockIdx.x * PLS;
    for (int idx = tid; idx < 97 * 97; idx += 256) {
        int x = idx / 97, y = idx - x * 97;
        float v = 0.f;
        if (x <= 95 && y >= 1 && x <= y - 1) { v = s[x][y - 1]; if (isMin) v = -v; }
        Rp[x * RS + y] = v;
    }
}

// ---------------- projection step 0: A = r@Wf, B = r@Wr ----------------
__global__ __launch_bounds__(256) void proj0_kernel(const float* __restrict__ R, const float* __restrict__ W,
                                                    float* __restrict__ A, float* __restrict__ B) {
    const int bh = blockIdx.y, b = bh >> 4, h = bh & 15;
    const int p = blockIdx.x * 256 + threadIdx.x;
    if (p >= NP) return;
    const int x = p / 97, y = p - x * 97;
    const int off = x * RS + y;
    const float* Rb = R + (size_t)b * 32 * PLS + off;
    float accA = 0.f, accB = 0.f;
#pragma unroll
    for (int d = 0; d < 32; ++d) {
        float rv = Rb[(size_t)d * PLS];
        accA += rv * W[d * 16 + h];
        accB += rv * W[(32 + d) * 16 + h];
    }
    A[(size_t)bh * PLS + off] = accA;
    B[(size_t)bh * PLS + off] = accB;
}

// ---------------- projection step 1: A = [f1,r]@Wf, B = r@Wr ----------------
__global__ __launch_bounds__(256) void proj1_kernel(const float* __restrict__ R, const float* __restrict__ F1,
                                                    const float* __restrict__ W,
                                                    float* __restrict__ A, float* __restrict__ B) {
    const int bh = blockIdx.y, b = bh >> 4, h = bh & 15;
    const int p = blockIdx.x * 256 + threadIdx.x;
    if (p >= NP) return;
    const int x = p / 97, y = p - x * 97;
    const int off = x * RS + y;
    const float* Rb = R  + (size_t)b * 32 * PLS + off;
    const float* Fb = F1 + (size_t)b * 16 * PLS + off;
    float accA = 0.f, accB = 0.f;
#pragma unroll
    for (int c = 0; c < 16; ++c) accA += Fb[(size_t)c * PLS] * W[c * 16 + h];
#pragma unroll
    for (int d = 0; d < 32; ++d) {
        float rv = Rb[(size_t)d * PLS];
        accA += rv * W[(16 + d) * 16 + h];
        accB += rv * W[(48 + d) * 16 + h];
    }
    A[(size_t)bh * PLS + off] = accA;
    B[(size_t)bh * PLS + off] = accB;
}

// ---------------- max-plus "GEMM": F[i][j] = sigmoid(bias + max_k A[i][k]+B[k][j]) ----------------
// 32i x 64j tiles, 2x4 outputs/thread: per k, 1 ds_read_b64 + 1 ds_read_b128 feed 16 VALU ops
// (vs 2 b64 per 8 ops at 2x2). grid: 8 tiles x 64 planes = 512 blocks (2/CU, 39.6 KB LDS each).
// All patterns individually proven: stride-68 float4 reads/stores (R2), stride-34 float2 reads (R7).
__global__ __launch_bounds__(256) void maxplus_kernel(const float* __restrict__ A, const float* __restrict__ Bm,
                                                      const float* __restrict__ bias, float* __restrict__ F) {
    __shared__ alignas(16) float As[97 * ASTR];  // As[k][i-local] (transposed), 32 rows
    __shared__ alignas(16) float Bs[97 * BSTR];  // Bs[k][j-local], 64 cols
    const int tid = threadIdx.x;
    const int bh = blockIdx.y;
    const int h  = bh & 15;
    const int i0 = (blockIdx.x & 3) * 32;        // 4 i-tiles of 32 (covers 97 with pad)
    const int j0 = (blockIdx.x >> 2) * 64;       // 2 j-tiles of 64
    const float* Ab = A  + (size_t)bh * PLS;
    const float* Bb = Bm + (size_t)bh * PLS;

    for (int idx = tid; idx < 32 * 97; idx += 256) {      // A panel, transposed into LDS
        int r = idx / 97, k = idx - r * 97;               // consecutive tid -> consecutive k (coalesced)
        int ii = i0 + r;
        As[k * ASTR + r] = (ii < 97) ? Ab[ii * RS + k] : -1e30f;
    }
    for (int idx = tid; idx < 97 * 64; idx += 256) {      // B panel, direct
        int k = idx >> 6, c = idx & 63;                   // consecutive tid -> consecutive jj (coalesced)
        int jj = j0 + c;
        Bs[k * BSTR + c] = (jj < 97) ? Bb[k * RS + jj] : -1e30f;
    }
    __syncthreads();

    const int ty = tid >> 4, tx = tid & 15;               // rows i0+ty*2..+1, cols j0+tx*4..+3
    float acc[2][4];
#pragma unroll
    for (int r = 0; r < 2; ++r)
#pragma unroll
        for (int c = 0; c < 4; ++c) acc[r][c] = -1e30f;

#pragma unroll 4
    for (int k = 0; k < 97; ++k) {
        const float2 a2 = *reinterpret_cast<const float2*>(&As[k * ASTR + ty * 2]);
        const float4 b4 = *reinterpret_cast<const float4*>(&Bs[k * BSTR + tx * 4]);
        const float bc[4] = {b4.x, b4.y, b4.z, b4.w};
#pragma unroll
        for (int c = 0; c < 4; ++c) {
            acc[0][c] = fmaxf(acc[0][c], a2.x + bc[c]);
            acc[1][c] = fmaxf(acc[1][c], a2.y + bc[c]);
        }
    }

    const float bb = bias[h];
    float* Fb = F + (size_t)bh * PLS;
    const int col0 = j0 + tx * 4;
    const int row0 = i0 + ty * 2;
#pragma unroll
    for (int r = 0; r < 2; ++r) {
        const int row = row0 + r;
        if (row > 96) continue;
        if (col0 + 3 <= 96) {
            float4 o;
            o.x = sigm(acc[r][0] + bb);
            o.y = sigm(acc[r][1] + bb);
            o.z = sigm(acc[r][2] + bb);
            o.w = sigm(acc[r][3] + bb);
            *reinterpret_cast<float4*>(&Fb[row * RS + col0]) = o;
        } else {
            for (int c = 0; c < 4; ++c) {
                const int col = col0 + c;
                if (col <= 96) Fb[row * RS + col] = sigm(acc[r][c] + bb);
            }
        }
    }
}

// ---------------- final: out = sigmoid([f2,r] @ W2 + b2), cropped [:, :-1, 1:] ----------------
__global__ __launch_bounds__(256) void final_kernel(const float* __restrict__ R, const float* __restrict__ F2,
                                                    const float* __restrict__ W, const float* __restrict__ bias,
                                                    float* __restrict__ out) {
    const int p = blockIdx.x * 256 + threadIdx.x;
    if (p >= 4 * 96 * 96) return;
    const int oj = p % 96;
    const int t1 = p / 96;
    const int i  = t1 % 96;
    const int b  = t1 / 96;
    const int off = i * RS + (oj + 1);   // j = oj+1 (crop)
    const float* Fb = F2 + (size_t)b * 16 * PLS + off;
    const float* Rb = R  + (size_t)b * 32 * PLS + off;
    float acc[16];
#pragma unroll
    for (int o = 0; o < 16; ++o) acc[o] = bias[o];
#pragma unroll
    for (int c = 0; c < 16; ++c) {
        const float fv = Fb[(size_t)c * PLS];
#pragma unroll
        for (int o = 0; o < 16; ++o) acc[o] += fv * W[c * 16 + o];
    }
#pragma unroll
    for (int d = 0; d < 32; ++d) {
        const float rv = Rb[(size_t)d * PLS];
#pragma unroll
        for (int o = 0; o < 16; ++o) acc[o] += rv * W[(16 + d) * 16 + o];
    }
    float4* dst = reinterpret_cast<float4*>(out + (size_t)p * 16);
#pragma unroll
    for (int q = 0; q < 4; ++q) {
        float4 v;
        v.x = sigm(acc[q * 4 + 0]);
        v.y = sigm(acc[q * 4 + 1]);
        v.z = sigm(acc[q * 4 + 2]);
        v.w = sigm(acc[q * 4 + 3]);
        dst[q] = v;
    }
}

extern "C" void kernel_launch(void* const* d_in, const int* in_sizes, int n_in,
                              void* d_out, int out_size, void* d_ws, size_t ws_size,
                              hipStream_t stream) {
    const float* a  = (const float*)d_in[0];
    const float* W0 = (const float*)d_in[1];
    const float* b0 = (const float*)d_in[2];
    const float* W1 = (const float*)d_in[3];
    const float* b1 = (const float*)d_in[4];
    const float* W2 = (const float*)d_in[5];
    const float* b2 = (const float*)d_in[6];
    float* ws = (float*)d_ws;
    float* out = (float*)d_out;

    hipLaunchKernelGGL(pool_kernel, dim3(128), dim3(256), 0, stream, a, ws + OFF_R);
    hipLaunchKernelGGL(proj0_kernel, dim3(37, 64), dim3(256), 0, stream,
                       ws + OFF_R, W0, ws + OFF_A, ws + OFF_Bm);
    hipLaunchKernelGGL(maxplus_kernel, dim3(8, 64), dim3(256), 0, stream,
                       ws + OFF_A, ws + OFF_Bm, b0, ws + OFF_F1);
    hipLaunchKernelGGL(proj1_kernel, dim3(37, 64), dim3(256), 0, stream,
                       ws + OFF_R, ws + OFF_F1, W1, ws + OFF_A, ws + OFF_Bm);
    hipLaunchKernelGGL(maxplus_kernel, dim3(8, 64), dim3(256), 0, stream,
                       ws + OFF_A, ws + OFF_Bm, b1, ws + OFF_F2);
    hipLaunchKernelGGL(final_kernel, dim3(144), dim3(256), 0, stream,
                       ws + OFF_R, ws + OFF_F2, W2, b2, out);
}

// Round 10
// 149.470 us; speedup vs baseline: 1.0576x; 1.0576x over previous
//
#include <hip/hip_runtime.h>
#include <hip/hip_bf16.h>

#define RS   100            // row stride (floats) of a 97x97 plane (padded for float4 alignment)
#define PLS  9700           // plane stride = 97 rows * RS
#define NP   9409           // 97*97 valid elements per plane
#define LSTR 34             // maxplus LDS row stride: bank=(2k+r)%32 -> worst 2-way (free); 8B-aligned

// ws layout (float offsets) — weights read directly from d_in (fp32)
#define OFF_R   0                          // 4*32 planes (pooled relations, padded/shifted)
#define OFF_A   (OFF_R  + 4*32*PLS)        // 4*16 planes (ft projection)
#define OFF_Bm  (OFF_A  + 4*16*PLS)        // 4*16 planes (rt projection)
#define OFF_F1  (OFF_Bm + 4*16*PLS)        // 4*16 planes (dp step-0 output)
#define OFF_F2  (OFF_F1 + 4*16*PLS)        // 4*16 planes (dp step-1 output)
// total = 384 planes * 9700 * 4 B = 14.9 MB of ws

__device__ __forceinline__ float sigm(float x) { return 1.0f / (1.0f + __expf(-x)); }

// ---------------- interval pooling (max & min) + pad -> R planes ----------------
__global__ __launch_bounds__(256) void pool_kernel(const float* __restrict__ a, float* __restrict__ R) {
    __shared__ float s[96][97];   // +1 pad: scans hit distinct banks both directions
    const int tid = threadIdx.x;
    const int b  = blockIdx.x >> 5;
    const int ch = blockIdx.x & 31;
    const int d  = ch & 15;
    const bool isMin = (ch >= 16);

    for (int idx = tid; idx < 96 * 96; idx += 256) {
        int i = idx / 96, j = idx - i * 96;
        float v = a[((size_t)(b * 96 + i) * 96 + j) * 16 + d];
        if (isMin) v = -v;
        s[i][j] = (j >= i) ? v : -1e30f;
    }
    __syncthreads();
    if (tid < 96) {              // reverse cummax over i (thread = column j)
        int j = tid; float run = -1e30f;
#pragma unroll 4
        for (int i = 95; i >= 0; --i) { run = fmaxf(run, s[i][j]); s[i][j] = run; }
    }
    __syncthreads();
    if (tid < 96) {              // forward cummax over j (thread = row i)
        int i = tid; float run = -1e30f;
#pragma unroll 4
        for (int j = 0; j < 96; ++j) { run = fmaxf(run, s[i][j]); s[i][j] = run; }
    }
    __syncthreads();
    float* Rp = R + (size_t)blockIdx.x * PLS;
    for (int idx = tid; idx < 97 * 97; idx += 256) {
        int x = idx / 97, y = idx - x * 97;
        float v = 0.f;
        if (x <= 95 && y >= 1 && x <= y - 1) { v = s[x][y - 1]; if (isMin) v = -v; }
        Rp[x * RS + y] = v;
    }
}

// ---------------- projection step 0: A = r@Wf, B = r@Wr ----------------
// 2 h-channels per thread: each R point-read feeds h0 and h1 (halves L2 read traffic).
// grid (37, 32): blockIdx.y = b*8 + hpair.
__global__ __launch_bounds__(256) void proj0_kernel(const float* __restrict__ R, const float* __restrict__ W,
                                                    float* __restrict__ A, float* __restrict__ B) {
    const int by = blockIdx.y, b = by >> 3, hp = by & 7;
    const int h0 = hp * 2, h1 = h0 + 1;
    const int p = blockIdx.x * 256 + threadIdx.x;
    if (p >= NP) return;
    const int x = p / 97, y = p - x * 97;
    const int off = x * RS + y;
    const float* Rb = R + (size_t)b * 32 * PLS + off;
    float accA0 = 0.f, accA1 = 0.f, accB0 = 0.f, accB1 = 0.f;
#pragma unroll
    for (int d = 0; d < 32; ++d) {
        float rv = Rb[(size_t)d * PLS];
        accA0 += rv * W[d * 16 + h0];
        accA1 += rv * W[d * 16 + h1];
        accB0 += rv * W[(32 + d) * 16 + h0];
        accB1 += rv * W[(32 + d) * 16 + h1];
    }
    A[(size_t)(b * 16 + h0) * PLS + off] = accA0;
    A[(size_t)(b * 16 + h1) * PLS + off] = accA1;
    B[(size_t)(b * 16 + h0) * PLS + off] = accB0;
    B[(size_t)(b * 16 + h1) * PLS + off] = accB1;
}

// ---------------- projection step 1: A = [f1,r]@Wf, B = r@Wr ----------------
// W1 (80x16): rows 0..15 -> f1, 16..47 -> r (Wf), 48..79 -> r (Wr). 2 h per thread.
__global__ __launch_bounds__(256) void proj1_kernel(const float* __restrict__ R, const float* __restrict__ F1,
                                                    const float* __restrict__ W,
                                                    float* __restrict__ A, float* __restrict__ B) {
    const int by = blockIdx.y, b = by >> 3, hp = by & 7;
    const int h0 = hp * 2, h1 = h0 + 1;
    const int p = blockIdx.x * 256 + threadIdx.x;
    if (p >= NP) return;
    const int x = p / 97, y = p - x * 97;
    const int off = x * RS + y;
    const float* Rb = R  + (size_t)b * 32 * PLS + off;
    const float* Fb = F1 + (size_t)b * 16 * PLS + off;
    float accA0 = 0.f, accA1 = 0.f, accB0 = 0.f, accB1 = 0.f;
#pragma unroll
    for (int c = 0; c < 16; ++c) {
        float fv = Fb[(size_t)c * PLS];
        accA0 += fv * W[c * 16 + h0];
        accA1 += fv * W[c * 16 + h1];
    }
#pragma unroll
    for (int d = 0; d < 32; ++d) {
        float rv = Rb[(size_t)d * PLS];
        accA0 += rv * W[(16 + d) * 16 + h0];
        accA1 += rv * W[(16 + d) * 16 + h1];
        accB0 += rv * W[(48 + d) * 16 + h0];
        accB1 += rv * W[(48 + d) * 16 + h1];
    }
    A[(size_t)(b * 16 + h0) * PLS + off] = accA0;
    A[(size_t)(b * 16 + h1) * PLS + off] = accA1;
    B[(size_t)(b * 16 + h0) * PLS + off] = accB0;
    B[(size_t)(b * 16 + h1) * PLS + off] = accB1;
}

// ---------------- max-plus "GEMM": F[i][j] = sigmoid(bias + max_k A[i][k]+B[k][j]) ----------------
// R7 winner config: 32x32 tiles, 2x2/thread, 1024 blocks (4/CU, 16 waves/CU hides staging latency).
// LDS stride 34: staging writes 2-way max (free), compute reads 2-way max.
__global__ __launch_bounds__(256) void maxplus_kernel(const float* __restrict__ A, const float* __restrict__ Bm,
                                                      const float* __restrict__ bias, float* __restrict__ F) {
    __shared__ alignas(16) float As[97 * LSTR];  // As[k][i-local] (transposed)
    __shared__ alignas(16) float Bs[97 * LSTR];  // Bs[k][j-local]
    const int tid = threadIdx.x;
    const int bh = blockIdx.y;
    const int h  = bh & 15;
    const int i0 = (blockIdx.x & 3) * 32;
    const int j0 = (blockIdx.x >> 2) * 32;
    const float* Ab = A  + (size_t)bh * PLS;
    const float* Bb = Bm + (size_t)bh * PLS;

    for (int idx = tid; idx < 32 * 97; idx += 256) {      // A panel, transposed into LDS
        int r = idx / 97, k = idx - r * 97;               // consecutive tid -> consecutive k (coalesced)
        int ii = i0 + r;
        As[k * LSTR + r] = (ii < 97) ? Ab[ii * RS + k] : -1e30f;
    }
    for (int idx = tid; idx < 97 * 32; idx += 256) {      // B panel, direct
        int k = idx >> 5, c = idx & 31;                   // consecutive tid -> consecutive jj (coalesced)
        int jj = j0 + c;
        Bs[k * LSTR + c] = (jj < 97) ? Bb[k * RS + jj] : -1e30f;
    }
    __syncthreads();

    const int ty = tid >> 4, tx = tid & 15;
    float a00 = -1e30f, a01 = -1e30f, a10 = -1e30f, a11 = -1e30f;

#pragma unroll 4
    for (int k = 0; k < 97; ++k) {
        const float2 a2 = *reinterpret_cast<const float2*>(&As[k * LSTR + ty * 2]);  // broadcast in ty-group
        const float2 b2 = *reinterpret_cast<const float2*>(&Bs[k * LSTR + tx * 2]);  // spans all banks
        a00 = fmaxf(a00, a2.x + b2.x);
        a01 = fmaxf(a01, a2.x + b2.y);
        a10 = fmaxf(a10, a2.y + b2.x);
        a11 = fmaxf(a11, a2.y + b2.y);
    }

    const float bb = bias[h];
    float* Fb = F + (size_t)bh * PLS;
    const int col0 = j0 + tx * 2;
    const int row0 = i0 + ty * 2;
    float v[2][2] = {{a00, a01}, {a10, a11}};
#pragma unroll
    for (int r = 0; r < 2; ++r) {
        const int row = row0 + r;
        if (row > 96) continue;
        if (col0 + 1 <= 96) {
            float2 o;
            o.x = sigm(v[r][0] + bb);
            o.y = sigm(v[r][1] + bb);
            *reinterpret_cast<float2*>(&Fb[row * RS + col0]) = o;
        } else if (col0 <= 96) {
            Fb[row * RS + col0] = sigm(v[r][0] + bb);
        }
    }
}

// ---------------- final: out = sigmoid([f2,r] @ W2 + b2), cropped [:, :-1, 1:] ----------------
__global__ __launch_bounds__(256) void final_kernel(const float* __restrict__ R, const float* __restrict__ F2,
                                                    const float* __restrict__ W, const float* __restrict__ bias,
                                                    float* __restrict__ out) {
    const int p = blockIdx.x * 256 + threadIdx.x;
    if (p >= 4 * 96 * 96) return;
    const int oj = p % 96;
    const int t1 = p / 96;
    const int i  = t1 % 96;
    const int b  = t1 / 96;
    const int off = i * RS + (oj + 1);   // j = oj+1 (crop)
    const float* Fb = F2 + (size_t)b * 16 * PLS + off;
    const float* Rb = R  + (size_t)b * 32 * PLS + off;
    float acc[16];
#pragma unroll
    for (int o = 0; o < 16; ++o) acc[o] = bias[o];
#pragma unroll
    for (int c = 0; c < 16; ++c) {
        const float fv = Fb[(size_t)c * PLS];
#pragma unroll
        for (int o = 0; o < 16; ++o) acc[o] += fv * W[c * 16 + o];
    }
#pragma unroll
    for (int d = 0; d < 32; ++d) {
        const float rv = Rb[(size_t)d * PLS];
#pragma unroll
        for (int o = 0; o < 16; ++o) acc[o] += rv * W[(16 + d) * 16 + o];
    }
    float4* dst = reinterpret_cast<float4*>(out + (size_t)p * 16);
#pragma unroll
    for (int q = 0; q < 4; ++q) {
        float4 v;
        v.x = sigm(acc[q * 4 + 0]);
        v.y = sigm(acc[q * 4 + 1]);
        v.z = sigm(acc[q * 4 + 2]);
        v.w = sigm(acc[q * 4 + 3]);
        dst[q] = v;
    }
}

extern "C" void kernel_launch(void* const* d_in, const int* in_sizes, int n_in,
                              void* d_out, int out_size, void* d_ws, size_t ws_size,
                              hipStream_t stream) {
    const float* a  = (const float*)d_in[0];
    const float* W0 = (const float*)d_in[1];
    const float* b0 = (const float*)d_in[2];
    const float* W1 = (const float*)d_in[3];
    const float* b1 = (const float*)d_in[4];
    const float* W2 = (const float*)d_in[5];
    const float* b2 = (const float*)d_in[6];
    float* ws = (float*)d_ws;
    float* out = (float*)d_out;

    hipLaunchKernelGGL(pool_kernel, dim3(128), dim3(256), 0, stream, a, ws + OFF_R);
    hipLaunchKernelGGL(proj0_kernel, dim3(37, 32), dim3(256), 0, stream,
                       ws + OFF_R, W0, ws + OFF_A, ws + OFF_Bm);
    hipLaunchKernelGGL(maxplus_kernel, dim3(16, 64), dim3(256), 0, stream,
                       ws + OFF_A, ws + OFF_Bm, b0, ws + OFF_F1);
    hipLaunchKernelGGL(proj1_kernel, dim3(37, 32), dim3(256), 0, stream,
                       ws + OFF_R, ws + OFF_F1, W1, ws + OFF_A, ws + OFF_Bm);
    hipLaunchKernelGGL(maxplus_kernel, dim3(16, 64), dim3(256), 0, stream,
                       ws + OFF_A, ws + OFF_Bm, b1, ws + OFF_F2);
    hipLaunchKernelGGL(final_kernel, dim3(144), dim3(256), 0, stream,
                       ws + OFF_R, ws + OFF_F2, W2, b2, out);
}